// Round 1
// baseline (212.597 us; speedup 1.0000x reference)
//
#include <hip/hip_runtime.h>
#include <hip/hip_bf16.h>
#include <math.h>

#define B_SZ    8
#define T_LEN   4096
#define DIN     256
#define DOUT    256
#define NST     512
#define M_ROWS  (B_SZ * T_LEN)   // 32768
#define N1      (2 * NST)        // 1024: cols [0,512)=real plane, [512,1024)=imag plane
#define K2      (N1 + DIN)       // 1280
#define CHL     128              // scan chunk length
#define NCH     (T_LEN / CHL)    // 32
#define XW      1032             // 1024 + 8 pad: 2-way bank alias on b128 reads (free)

typedef __attribute__((ext_vector_type(8))) short bf16x8;
typedef __attribute__((ext_vector_type(4))) float f32x4;
typedef __hip_bfloat16 bf16;

// ws byte offsets (identical to prior rounds; Pcar slot unused)
#define OFF_UBF  67108864
#define OFF_WP   83886080
#define OFF_W2   84410368
#define OFF_LAM  85065728
#define OFF_LAML 85069824
#define OFF_SSUM 85073920

__device__ __forceinline__ void gl_lds16(const bf16* g, bf16* l) {
    __builtin_amdgcn_global_load_lds(
        (const __attribute__((address_space(1))) void*)g,
        (__attribute__((address_space(3))) void*)l, 16, 0, 0);
}

// ---- prep (verbatim): conv_u + pack_w1 + pack_w2, split-plane ----
__global__ __launch_bounds__(256) void prep(const float* __restrict__ u,
        const float* __restrict__ nu_log, const float* __restrict__ theta_log,
        const float* __restrict__ gamma_log,
        const float* __restrict__ B_real, const float* __restrict__ B_imag,
        const float* __restrict__ C_real, const float* __restrict__ C_imag,
        const float* __restrict__ Dm,
        bf16* __restrict__ ub, bf16* __restrict__ Wp, bf16* __restrict__ W2,
        float* __restrict__ lam, float* __restrict__ lamL) {
    int bid = blockIdx.x, tid = threadIdx.x;
    if (bid < 8192) {                       // u -> bf16
        int i = bid * 256 + tid;
        float4 v = ((const float4*)u)[i];
        union { bf16 h[4]; uint2 u2; } p;
        p.h[0] = __float2bfloat16(v.x); p.h[1] = __float2bfloat16(v.y);
        p.h[2] = __float2bfloat16(v.z); p.h[3] = __float2bfloat16(v.w);
        ((uint2*)ub)[i] = p.u2;
    } else if (bid < 9216) {                // Wp (split planes) + lam/lamL
        int c = bid - 8192;                 // 0..1023
        int n = c & (NST - 1);
        float g = expf(gamma_log[n]);
        const float* src = (c < NST) ? (B_real + (size_t)n * DIN)
                                     : (B_imag + (size_t)n * DIN);
        Wp[(size_t)c * DIN + tid] = __float2bfloat16(g * src[tid]);
        int idx = c * 256 + tid;
        if (idx < NST) {
            float lm = expf(-expf(nu_log[idx]));
            float th = expf(theta_log[idx]);
            float lr = lm * cosf(th), li = lm * sinf(th);
            lam[idx] = lr; lam[NST + idx] = li;
            float ar = lr, ai = li;
#pragma unroll
            for (int q = 0; q < 7; ++q) {   // lambda^128
                float nr = ar * ar - ai * ai;
                float ni = 2.f * ar * ai;
                ar = nr; ai = ni;
            }
            lamL[idx] = ar; lamL[NST + idx] = ai;
        }
    } else {                                // W2 = [2Cr | -2Ci | D] split
        int idx = (bid - 9216) * 256 + tid;
        if (idx < DOUT * K2) {
            int o = idx / K2, c = idx - o * K2;
            float v;
            if (c < NST)            v =  2.0f * C_real[(size_t)o * NST + c];
            else if (c < 2 * NST)   v = -2.0f * C_imag[(size_t)o * NST + (c - NST)];
            else                    v =  Dm[(size_t)o * DIN + (c - 2 * NST)];
            W2[idx] = __float2bfloat16(v);
        }
    }
}

// ---- GEMM1 (verbatim) with LDS-packed coalesced Bu stores ----
__global__ __launch_bounds__(256) void gemm1(const bf16* __restrict__ u,
                                             const bf16* __restrict__ Wp,
                                             bf16* __restrict__ Bu) {
    __shared__ bf16 As[128 * 32];
    __shared__ bf16 Bs[128 * 32];
    __shared__ bf16 Cs[128 * 136];       // +8 pad: spreads 2B-scatter banks
    const int tid = threadIdx.x;
    const int m0 = blockIdx.x * 128, n0 = blockIdx.y * 128;
    const int lane = tid & 63, w = tid >> 6;
    const int wm = (w >> 1) * 64, wn = (w & 1) * 64;
    const int lr16 = lane & 15, kq = (lane >> 4) * 8;
    const int srow = tid >> 2, scol = (tid & 3) * 8;

    f32x4 acc[4][4] = {};
    for (int k0 = 0; k0 < DIN; k0 += 32) {
        gl_lds16(u  + (size_t)(m0 + srow) * DIN + k0 + scol,       &As[tid * 8]);
        gl_lds16(u  + (size_t)(m0 + 64 + srow) * DIN + k0 + scol,  &As[2048 + tid * 8]);
        gl_lds16(Wp + (size_t)(n0 + srow) * DIN + k0 + scol,       &Bs[tid * 8]);
        gl_lds16(Wp + (size_t)(n0 + 64 + srow) * DIN + k0 + scol,  &Bs[2048 + tid * 8]);
        __syncthreads();
        bf16x8 af[4], bfr[4];
#pragma unroll
        for (int i = 0; i < 4; ++i)
            af[i] = *(const bf16x8*)(&As[(wm + i * 16 + lr16) * 32 + kq]);
#pragma unroll
        for (int j = 0; j < 4; ++j)
            bfr[j] = *(const bf16x8*)(&Bs[(wn + j * 16 + lr16) * 32 + kq]);
#pragma unroll
        for (int i = 0; i < 4; ++i)
#pragma unroll
            for (int j = 0; j < 4; ++j)
                acc[i][j] = __builtin_amdgcn_mfma_f32_16x16x32_bf16(af[i], bfr[j], acc[i][j], 0, 0, 0);
        __syncthreads();
    }
    const int crow = (lane >> 4) * 4, ccol = lane & 15;
#pragma unroll
    for (int i = 0; i < 4; ++i)
#pragma unroll
        for (int j = 0; j < 4; ++j)
#pragma unroll
            for (int r = 0; r < 4; ++r)
                Cs[(wm + i * 16 + crow + r) * 136 + wn + j * 16 + ccol] =
                    __float2bfloat16(acc[i][j][r]);
    __syncthreads();
#pragma unroll
    for (int p = 0; p < 8; ++p) {
        int row = p * 16 + (tid >> 4);
        int colg = (tid & 15) * 8;
        *(uint4*)(&Bu[(size_t)(m0 + row) * N1 + n0 + colg]) =
            *(const uint4*)(&Cs[row * 136 + colg]);
    }
}

// ---- scan phase 1 (verbatim): per-(b,n,chunk) final state ----
__global__ __launch_bounds__(512) void scan1(const bf16* __restrict__ Bu,
                                             const float* __restrict__ lam,
                                             float* __restrict__ Ssum) {
    int n = threadIdx.x;
    int c = blockIdx.x;
    int b = blockIdx.y;
    float lr = lam[n], li = lam[NST + n];
    const bf16* base = Bu + ((size_t)b * T_LEN + (size_t)c * CHL) * N1;
    float sr = 0.f, si = 0.f;
    for (int j = 0; j < CHL; ++j) {
        float br = __bfloat162float(base[(size_t)j * N1 + n]);
        float bi = __bfloat162float(base[(size_t)j * N1 + NST + n]);
        float tr = lr * sr - li * si + br;
        float ti = lr * si + li * sr + bi;
        sr = tr; si = ti;
    }
    size_t o = ((size_t)b * NCH + c) * N1 + n;
    Ssum[o] = sr; Ssum[o + NST] = si;
}

// ---- FUSED scan3 + GEMM2 ----
// Per block (b,c): inline carry from Ssum (bitwise = old scan3), scan a
// 64-timestep half into LDS Xs (bf16, padded rows), then GEMM that half
// against W2 with A fully LDS-resident. x is never written to HBM; Bu is
// read exactly once. u-tail (K=[1024,1280)) reg-staged into Xs cols [0,256)
// after the x-panels are consumed. K-order and rounding points identical to
// the old scan3+gemm2 pair -> bitwise-identical y.
__global__ __launch_bounds__(512, 2) void scan_gemm2(
        const bf16* __restrict__ Bu, const bf16* __restrict__ u,
        const bf16* __restrict__ W2, const float* __restrict__ lam,
        const float* __restrict__ lamL, const float* __restrict__ Ssum,
        float* __restrict__ y) {
    __shared__ bf16 Xs[64 * XW];      // 132096 B
    __shared__ bf16 Bs[256 * 32];     // 16384 B  (total 148480 <= 160 KiB)
    const int tid = threadIdx.x;
    const int c = blockIdx.x, b = blockIdx.y;
    const int n = tid;                               // state id 0..511

    // carry: p = L*p + S_c' over c' < c (Ssum is 1 MB -> L2-resident)
    float lr = lam[n], li = lam[NST + n];
    float Lr = lamL[n], Li = lamL[NST + n];
    float xr = 0.f, xi = 0.f;
    for (int cp = 0; cp < c; ++cp) {
        size_t o = ((size_t)b * NCH + cp) * N1 + n;
        float sr = Ssum[o], si = Ssum[o + NST];
        float tr = Lr * xr - Li * xi + sr;
        float ti = Lr * xi + Li * xr + si;
        xr = tr; xi = ti;
    }

    const bf16* base = Bu + ((size_t)b * T_LEN + (size_t)c * CHL) * N1;
    const int row0 = b * T_LEN + c * CHL;
    const int lane = tid & 63, w = tid >> 6;
    const int wn = w * 32;                           // wave N-range (8 waves x 32)
    const int lr16 = lane & 15, kq = (lane >> 4) * 8;
    const int urow = tid >> 3, ucol = (tid & 7) * 32;
    const int brow = tid >> 1, bcol = (tid & 1) * 16;
    const int crow = (lane >> 4) * 4, ccol = lane & 15;

    for (int half = 0; half < 2; ++half) {
        // ---- scan 64 steps, x -> Xs (carry continues in regs across halves)
        for (int j = 0; j < 64; ++j) {
            int jj = half * 64 + j;
            float br = __bfloat162float(base[(size_t)jj * N1 + n]);
            float bi = __bfloat162float(base[(size_t)jj * N1 + NST + n]);
            float tr = lr * xr - li * xi + br;
            float ti = lr * xi + li * xr + bi;
            xr = tr; xi = ti;
            Xs[j * XW + n]       = __float2bfloat16(xr);
            Xs[j * XW + NST + n] = __float2bfloat16(xi);
        }
        // issue u-tile loads early (consumed at panel 31 boundary)
        const bf16* up = u + (size_t)(row0 + half * 64 + urow) * DIN + ucol;
        uint4 ur0 = *(const uint4*)(up);
        uint4 ur1 = *(const uint4*)(up + 8);
        uint4 ur2 = *(const uint4*)(up + 16);
        uint4 ur3 = *(const uint4*)(up + 24);
        // prologue: stage Bs panel 0 (k0g = 0); each wave moves 2x 1KB chunks
        {
            int ch0 = w * 2, ch1 = w * 2 + 1;
            int rr0 = ch0 * 16 + (lane >> 2), rr1 = ch1 * 16 + (lane >> 2);
            int cb = (lane & 3) * 8;
            gl_lds16(W2 + (size_t)rr0 * K2 + cb, &Bs[ch0 * 512 + lane * 8]);
            gl_lds16(W2 + (size_t)rr1 * K2 + cb, &Bs[ch1 * 512 + lane * 8]);
        }
        __syncthreads();                 // Xs visible + Bs panel 0 landed

        f32x4 acc[4][2] = {};
        for (int p = 0; p < 40; ++p) {
            // reg-prefetch next W2 panel (T14: issue-early / write-late)
            uint4 r0, r1;
            const bool havep = (p + 1) < 40;
            if (havep) {
                int pn = p + 1;
                int k0g = pn < 32 ? pn * 32 : 1024 + (pn - 32) * 32;
                const bf16* wp2 = W2 + (size_t)brow * K2 + k0g + bcol;
                r0 = *(const uint4*)(wp2);
                r1 = *(const uint4*)(wp2 + 8);
            }
            int ca0 = p < 32 ? p * 32 : (p - 32) * 32;
            bf16x8 af[4], bfr[2];
#pragma unroll
            for (int i = 0; i < 4; ++i)
                af[i] = *(const bf16x8*)(&Xs[(i * 16 + lr16) * XW + ca0 + kq]);
#pragma unroll
            for (int j = 0; j < 2; ++j)
                bfr[j] = *(const bf16x8*)(&Bs[(wn + j * 16 + lr16) * 32 + kq]);
#pragma unroll
            for (int i = 0; i < 4; ++i)
#pragma unroll
                for (int j = 0; j < 2; ++j)
                    acc[i][j] = __builtin_amdgcn_mfma_f32_16x16x32_bf16(af[i], bfr[j], acc[i][j], 0, 0, 0);
            __syncthreads();             // all waves done reading Bs/Xs panel p
            if (p == 31) {               // x-panels consumed cols [0,256): stage u there
                bf16* xd = &Xs[urow * XW + ucol];
                *(uint4*)(xd)      = ur0;
                *(uint4*)(xd + 8)  = ur1;
                *(uint4*)(xd + 16) = ur2;
                *(uint4*)(xd + 24) = ur3;
            }
            if (havep) {
                bf16* bd = &Bs[brow * 32 + bcol];
                *(uint4*)(bd)     = r0;
                *(uint4*)(bd + 8) = r1;
            }
            __syncthreads();             // writes visible before panel p+1
        }
        // epilogue: register-only, no barrier needed before next half's scan
#pragma unroll
        for (int i = 0; i < 4; ++i)
#pragma unroll
            for (int j = 0; j < 2; ++j)
#pragma unroll
                for (int r = 0; r < 4; ++r)
                    y[(size_t)(row0 + half * 64 + i * 16 + crow + r) * DOUT + wn + j * 16 + ccol] =
                        acc[i][j][r];
    }
}

extern "C" void kernel_launch(void* const* d_in, const int* in_sizes, int n_in,
                              void* d_out, int out_size, void* d_ws, size_t ws_size,
                              hipStream_t stream) {
    const float* u_in      = (const float*)d_in[0];
    const float* nu_log    = (const float*)d_in[1];
    const float* theta_log = (const float*)d_in[2];
    const float* gamma_log = (const float*)d_in[3];
    const float* B_real    = (const float*)d_in[4];
    const float* B_imag    = (const float*)d_in[5];
    const float* C_real    = (const float*)d_in[6];
    const float* C_imag    = (const float*)d_in[7];
    const float* Dm        = (const float*)d_in[8];
    float* y = (float*)d_out;
    char* ws = (char*)d_ws;

    bf16*  Bu   = (bf16*)ws;
    bf16*  u_bf = (bf16*)(ws + OFF_UBF);
    bf16*  Wp   = (bf16*)(ws + OFF_WP);
    bf16*  W2   = (bf16*)(ws + OFF_W2);
    float* lam  = (float*)(ws + OFF_LAM);
    float* lamL = (float*)(ws + OFF_LAML);
    float* Ssum = (float*)(ws + OFF_SSUM);

    prep<<<10496, 256, 0, stream>>>(u_in, nu_log, theta_log, gamma_log,
                                    B_real, B_imag, C_real, C_imag, Dm,
                                    u_bf, Wp, W2, lam, lamL);
    gemm1<<<dim3(M_ROWS / 128, N1 / 128), 256, 0, stream>>>(u_bf, Wp, Bu);
    scan1<<<dim3(NCH, B_SZ), 512, 0, stream>>>(Bu, lam, Ssum);
    scan_gemm2<<<dim3(NCH, B_SZ), 512, 0, stream>>>(Bu, u_bf, W2, lam, lamL, Ssum, y);
}

// Round 2
// 207.122 us; speedup vs baseline: 1.0264x; 1.0264x over previous
//
#include <hip/hip_runtime.h>
#include <hip/hip_bf16.h>
#include <math.h>

#define B_SZ    8
#define T_LEN   4096
#define DIN     256
#define DOUT    256
#define NST     512
#define M_ROWS  (B_SZ * T_LEN)   // 32768
#define N1      (2 * NST)        // 1024: cols [0,512)=real plane, [512,1024)=imag plane
#define K2      (N1 + DIN)       // 1280
#define CHL     32               // scan chunk length (was 128): 4x blocks, 4x less serial depth
#define NCH     (T_LEN / CHL)    // 128

typedef __attribute__((ext_vector_type(8))) short bf16x8;
typedef __attribute__((ext_vector_type(4))) float f32x4;
typedef __hip_bfloat16 bf16;

// ws byte offsets (Ssum now 4 MB: 8*128*1024*4)
#define OFF_UBF  67108864
#define OFF_WP   83886080
#define OFF_W2   84410368
#define OFF_LAM  85065728
#define OFF_LAML 85069824
#define OFF_SSUM 85073920

__device__ __forceinline__ void gl_lds16(const bf16* g, bf16* l) {
    __builtin_amdgcn_global_load_lds(
        (const __attribute__((address_space(1))) void*)g,
        (__attribute__((address_space(3))) void*)l, 16, 0, 0);
}

// ---- prep: conv_u + pack_w1 + pack_w2, split-plane; lamL = lambda^CHL ----
__global__ __launch_bounds__(256) void prep(const float* __restrict__ u,
        const float* __restrict__ nu_log, const float* __restrict__ theta_log,
        const float* __restrict__ gamma_log,
        const float* __restrict__ B_real, const float* __restrict__ B_imag,
        const float* __restrict__ C_real, const float* __restrict__ C_imag,
        const float* __restrict__ Dm,
        bf16* __restrict__ ub, bf16* __restrict__ Wp, bf16* __restrict__ W2,
        float* __restrict__ lam, float* __restrict__ lamL) {
    int bid = blockIdx.x, tid = threadIdx.x;
    if (bid < 8192) {                       // u -> bf16
        int i = bid * 256 + tid;
        float4 v = ((const float4*)u)[i];
        union { bf16 h[4]; uint2 u2; } p;
        p.h[0] = __float2bfloat16(v.x); p.h[1] = __float2bfloat16(v.y);
        p.h[2] = __float2bfloat16(v.z); p.h[3] = __float2bfloat16(v.w);
        ((uint2*)ub)[i] = p.u2;
    } else if (bid < 9216) {                // Wp (split planes) + lam/lamL
        int c = bid - 8192;                 // 0..1023
        int n = c & (NST - 1);
        float g = expf(gamma_log[n]);
        const float* src = (c < NST) ? (B_real + (size_t)n * DIN)
                                     : (B_imag + (size_t)n * DIN);
        Wp[(size_t)c * DIN + tid] = __float2bfloat16(g * src[tid]);
        int idx = c * 256 + tid;
        if (idx < NST) {
            float lm = expf(-expf(nu_log[idx]));
            float th = expf(theta_log[idx]);
            float lr = lm * cosf(th), li = lm * sinf(th);
            lam[idx] = lr; lam[NST + idx] = li;
            float ar = lr, ai = li;
#pragma unroll
            for (int q = 0; q < 5; ++q) {   // lambda^32 (2^5 = CHL)
                float nr = ar * ar - ai * ai;
                float ni = 2.f * ar * ai;
                ar = nr; ai = ni;
            }
            lamL[idx] = ar; lamL[NST + idx] = ai;
        }
    } else {                                // W2 = [2Cr | -2Ci | D] split
        int idx = (bid - 9216) * 256 + tid;
        if (idx < DOUT * K2) {
            int o = idx / K2, c = idx - o * K2;
            float v;
            if (c < NST)            v =  2.0f * C_real[(size_t)o * NST + c];
            else if (c < 2 * NST)   v = -2.0f * C_imag[(size_t)o * NST + (c - NST)];
            else                    v =  Dm[(size_t)o * DIN + (c - 2 * NST)];
            W2[idx] = __float2bfloat16(v);
        }
    }
}

// ---- GEMM1 (verbatim) with LDS-packed coalesced Bu stores ----
__global__ __launch_bounds__(256) void gemm1(const bf16* __restrict__ u,
                                             const bf16* __restrict__ Wp,
                                             bf16* __restrict__ Bu) {
    __shared__ bf16 As[128 * 32];
    __shared__ bf16 Bs[128 * 32];
    __shared__ bf16 Cs[128 * 136];       // +8 pad: spreads 2B-scatter banks
    const int tid = threadIdx.x;
    const int m0 = blockIdx.x * 128, n0 = blockIdx.y * 128;
    const int lane = tid & 63, w = tid >> 6;
    const int wm = (w >> 1) * 64, wn = (w & 1) * 64;
    const int lr16 = lane & 15, kq = (lane >> 4) * 8;
    const int srow = tid >> 2, scol = (tid & 3) * 8;

    f32x4 acc[4][4] = {};
    for (int k0 = 0; k0 < DIN; k0 += 32) {
        gl_lds16(u  + (size_t)(m0 + srow) * DIN + k0 + scol,       &As[tid * 8]);
        gl_lds16(u  + (size_t)(m0 + 64 + srow) * DIN + k0 + scol,  &As[2048 + tid * 8]);
        gl_lds16(Wp + (size_t)(n0 + srow) * DIN + k0 + scol,       &Bs[tid * 8]);
        gl_lds16(Wp + (size_t)(n0 + 64 + srow) * DIN + k0 + scol,  &Bs[2048 + tid * 8]);
        __syncthreads();
        bf16x8 af[4], bfr[4];
#pragma unroll
        for (int i = 0; i < 4; ++i)
            af[i] = *(const bf16x8*)(&As[(wm + i * 16 + lr16) * 32 + kq]);
#pragma unroll
        for (int j = 0; j < 4; ++j)
            bfr[j] = *(const bf16x8*)(&Bs[(wn + j * 16 + lr16) * 32 + kq]);
#pragma unroll
        for (int i = 0; i < 4; ++i)
#pragma unroll
            for (int j = 0; j < 4; ++j)
                acc[i][j] = __builtin_amdgcn_mfma_f32_16x16x32_bf16(af[i], bfr[j], acc[i][j], 0, 0, 0);
        __syncthreads();
    }
    const int crow = (lane >> 4) * 4, ccol = lane & 15;
#pragma unroll
    for (int i = 0; i < 4; ++i)
#pragma unroll
        for (int j = 0; j < 4; ++j)
#pragma unroll
            for (int r = 0; r < 4; ++r)
                Cs[(wm + i * 16 + crow + r) * 136 + wn + j * 16 + ccol] =
                    __float2bfloat16(acc[i][j][r]);
    __syncthreads();
#pragma unroll
    for (int p = 0; p < 8; ++p) {
        int row = p * 16 + (tid >> 4);
        int colg = (tid & 15) * 8;
        *(uint4*)(&Bu[(size_t)(m0 + row) * N1 + n0 + colg]) =
            *(const uint4*)(&Cs[row * 136 + colg]);
    }
}

// ---- scan phase 1: per-(b,n,chunk) final state. CHL=32 -> 1024 blocks ----
__global__ __launch_bounds__(512) void scan1(const bf16* __restrict__ Bu,
                                             const float* __restrict__ lam,
                                             float* __restrict__ Ssum) {
    int n = threadIdx.x;
    int c = blockIdx.x;
    int b = blockIdx.y;
    float lr = lam[n], li = lam[NST + n];
    const bf16* base = Bu + ((size_t)b * T_LEN + (size_t)c * CHL) * N1;
    float sr = 0.f, si = 0.f;
#pragma unroll 8
    for (int j = 0; j < CHL; ++j) {
        float br = __bfloat162float(base[(size_t)j * N1 + n]);
        float bi = __bfloat162float(base[(size_t)j * N1 + NST + n]);
        float tr = lr * sr - li * si + br;
        float ti = lr * si + li * sr + bi;
        sr = tr; si = ti;
    }
    size_t o = ((size_t)b * NCH + c) * N1 + n;
    Ssum[o] = sr; Ssum[o + NST] = si;
}

// ---- scan phase 3 with inline carry over Ssum (L2-resident, 4 MB) ----
__global__ __launch_bounds__(512) void scan3(bf16* __restrict__ Bu,
                                             const float* __restrict__ lam,
                                             const float* __restrict__ lamL,
                                             const float* __restrict__ Ssum) {
    int n = threadIdx.x, c = blockIdx.x, b = blockIdx.y;
    float lr = lam[n], li = lam[NST + n];
    float Lr = lamL[n], Li = lamL[NST + n];
    float pr = 0.f, pi = 0.f;
#pragma unroll 4
    for (int cp = 0; cp < c; ++cp) {
        size_t o = ((size_t)b * NCH + cp) * N1 + n;
        float sr = Ssum[o], si = Ssum[o + NST];
        float tr = Lr * pr - Li * pi + sr;
        float ti = Lr * pi + Li * pr + si;
        pr = tr; pi = ti;
    }
    float xr = pr, xi = pi;
    bf16* base = Bu + ((size_t)b * T_LEN + (size_t)c * CHL) * N1;
#pragma unroll 8
    for (int j = 0; j < CHL; ++j) {
        float br = __bfloat162float(base[(size_t)j * N1 + n]);
        float bi = __bfloat162float(base[(size_t)j * N1 + NST + n]);
        float tr = lr * xr - li * xi + br;
        float ti = lr * xi + li * xr + bi;
        xr = tr; xi = ti;
        base[(size_t)j * N1 + n]       = __float2bfloat16(xr);
        base[(size_t)j * N1 + NST + n] = __float2bfloat16(xi);
    }
}

// ---- GEMM2 (199-us baseline verbatim): y = [X | u_bf] @ W2^T ----
__global__ __launch_bounds__(512) void gemm2(const bf16* __restrict__ X,
                                             const bf16* __restrict__ u,
                                             const bf16* __restrict__ W2,
                                             float* __restrict__ y) {
    __shared__ bf16 As[128 * 32];
    __shared__ bf16 Bs[128 * 32];
    const int tid = threadIdx.x;
    const int m0 = blockIdx.x * 128, n0 = blockIdx.y * 128;
    const int lane = tid & 63, w = tid >> 6;
    const int wm = (w >> 2) * 64, wn = (w & 3) * 32;   // 2x4 wave grid, 64x32 each
    const int lr16 = lane & 15, kq = (lane >> 4) * 8;
    const int srow = tid >> 2, scol = (tid & 3) * 8;   // 512 threads cover 128 rows

    f32x4 acc[4][2] = {};
    for (int k0 = 0; k0 < K2; k0 += 32) {
        const bf16* Asrc; size_t lda; int kc;
        if (k0 < N1) { Asrc = X; lda = N1;  kc = k0; }
        else         { Asrc = u; lda = DIN; kc = k0 - N1; }
        gl_lds16(Asrc + (size_t)(m0 + srow) * lda + kc + scol, &As[tid * 8]);
        gl_lds16(W2 + (size_t)(n0 + srow) * K2 + k0 + scol,    &Bs[tid * 8]);
        __syncthreads();
        bf16x8 af[4], bfr[2];
#pragma unroll
        for (int i = 0; i < 4; ++i)
            af[i] = *(const bf16x8*)(&As[(wm + i * 16 + lr16) * 32 + kq]);
#pragma unroll
        for (int j = 0; j < 2; ++j)
            bfr[j] = *(const bf16x8*)(&Bs[(wn + j * 16 + lr16) * 32 + kq]);
#pragma unroll
        for (int i = 0; i < 4; ++i)
#pragma unroll
            for (int j = 0; j < 2; ++j)
                acc[i][j] = __builtin_amdgcn_mfma_f32_16x16x32_bf16(af[i], bfr[j], acc[i][j], 0, 0, 0);
        __syncthreads();
    }
    const int crow = (lane >> 4) * 4, ccol = lane & 15;
#pragma unroll
    for (int i = 0; i < 4; ++i)
#pragma unroll
        for (int j = 0; j < 2; ++j)
#pragma unroll
            for (int r = 0; r < 4; ++r)
                y[(size_t)(m0 + wm + i * 16 + crow + r) * DOUT + n0 + wn + j * 16 + ccol] = acc[i][j][r];
}

extern "C" void kernel_launch(void* const* d_in, const int* in_sizes, int n_in,
                              void* d_out, int out_size, void* d_ws, size_t ws_size,
                              hipStream_t stream) {
    const float* u_in      = (const float*)d_in[0];
    const float* nu_log    = (const float*)d_in[1];
    const float* theta_log = (const float*)d_in[2];
    const float* gamma_log = (const float*)d_in[3];
    const float* B_real    = (const float*)d_in[4];
    const float* B_imag    = (const float*)d_in[5];
    const float* C_real    = (const float*)d_in[6];
    const float* C_imag    = (const float*)d_in[7];
    const float* Dm        = (const float*)d_in[8];
    float* y = (float*)d_out;
    char* ws = (char*)d_ws;

    bf16*  Bu   = (bf16*)ws;
    bf16*  u_bf = (bf16*)(ws + OFF_UBF);
    bf16*  Wp   = (bf16*)(ws + OFF_WP);
    bf16*  W2   = (bf16*)(ws + OFF_W2);
    float* lam  = (float*)(ws + OFF_LAM);
    float* lamL = (float*)(ws + OFF_LAML);
    float* Ssum = (float*)(ws + OFF_SSUM);

    prep<<<10496, 256, 0, stream>>>(u_in, nu_log, theta_log, gamma_log,
                                    B_real, B_imag, C_real, C_imag, Dm,
                                    u_bf, Wp, W2, lam, lamL);
    gemm1<<<dim3(M_ROWS / 128, N1 / 128), 256, 0, stream>>>(u_bf, Wp, Bu);
    scan1<<<dim3(NCH, B_SZ), 512, 0, stream>>>(Bu, lam, Ssum);
    scan3<<<dim3(NCH, B_SZ), 512, 0, stream>>>(Bu, lam, lamL, Ssum);
    gemm2<<<dim3(M_ROWS / 128, DOUT / 128), 512, 0, stream>>>(Bu, u_bf, W2, y);
}

// Round 3
// 202.543 us; speedup vs baseline: 1.0496x; 1.0226x over previous
//
#include <hip/hip_runtime.h>
#include <hip/hip_bf16.h>
#include <math.h>

#define B_SZ    8
#define T_LEN   4096
#define DIN     256
#define DOUT    256
#define NST     512
#define M_ROWS  (B_SZ * T_LEN)   // 32768
#define N1      (2 * NST)        // 1024: cols [0,512)=real plane, [512,1024)=imag plane
#define K2      (N1 + DIN)       // 1280
#define CHL     128              // scan chunk length (reverted to baseline)
#define NCH     (T_LEN / CHL)    // 32

typedef __attribute__((ext_vector_type(8))) short bf16x8;
typedef __attribute__((ext_vector_type(4))) float f32x4;
typedef __hip_bfloat16 bf16;

// ws byte offsets (baseline layout)
#define OFF_UBF  67108864
#define OFF_WP   83886080
#define OFF_W2   84410368
#define OFF_LAM  85065728
#define OFF_LAML 85069824
#define OFF_SSUM 85073920

__device__ __forceinline__ void gl_lds16(const bf16* g, bf16* l) {
    __builtin_amdgcn_global_load_lds(
        (const __attribute__((address_space(1))) void*)g,
        (__attribute__((address_space(3))) void*)l, 16, 0, 0);
}

// ---- prep (baseline verbatim): conv_u + pack_w1 + pack_w2, split-plane ----
__global__ __launch_bounds__(256) void prep(const float* __restrict__ u,
        const float* __restrict__ nu_log, const float* __restrict__ theta_log,
        const float* __restrict__ gamma_log,
        const float* __restrict__ B_real, const float* __restrict__ B_imag,
        const float* __restrict__ C_real, const float* __restrict__ C_imag,
        const float* __restrict__ Dm,
        bf16* __restrict__ ub, bf16* __restrict__ Wp, bf16* __restrict__ W2,
        float* __restrict__ lam, float* __restrict__ lamL) {
    int bid = blockIdx.x, tid = threadIdx.x;
    if (bid < 8192) {                       // u -> bf16
        int i = bid * 256 + tid;
        float4 v = ((const float4*)u)[i];
        union { bf16 h[4]; uint2 u2; } p;
        p.h[0] = __float2bfloat16(v.x); p.h[1] = __float2bfloat16(v.y);
        p.h[2] = __float2bfloat16(v.z); p.h[3] = __float2bfloat16(v.w);
        ((uint2*)ub)[i] = p.u2;
    } else if (bid < 9216) {                // Wp (split planes) + lam/lamL
        int c = bid - 8192;                 // 0..1023
        int n = c & (NST - 1);
        float g = expf(gamma_log[n]);
        const float* src = (c < NST) ? (B_real + (size_t)n * DIN)
                                     : (B_imag + (size_t)n * DIN);
        Wp[(size_t)c * DIN + tid] = __float2bfloat16(g * src[tid]);
        int idx = c * 256 + tid;
        if (idx < NST) {
            float lm = expf(-expf(nu_log[idx]));
            float th = expf(theta_log[idx]);
            float lr = lm * cosf(th), li = lm * sinf(th);
            lam[idx] = lr; lam[NST + idx] = li;
            float ar = lr, ai = li;
#pragma unroll
            for (int q = 0; q < 7; ++q) {   // lambda^128
                float nr = ar * ar - ai * ai;
                float ni = 2.f * ar * ai;
                ar = nr; ai = ni;
            }
            lamL[idx] = ar; lamL[NST + idx] = ai;
        }
    } else {                                // W2 = [2Cr | -2Ci | D] split
        int idx = (bid - 9216) * 256 + tid;
        if (idx < DOUT * K2) {
            int o = idx / K2, c = idx - o * K2;
            float v;
            if (c < NST)            v =  2.0f * C_real[(size_t)o * NST + c];
            else if (c < 2 * NST)   v = -2.0f * C_imag[(size_t)o * NST + (c - NST)];
            else                    v =  Dm[(size_t)o * DIN + (c - 2 * NST)];
            W2[idx] = __float2bfloat16(v);
        }
    }
}

// ---- GEMM1 (baseline verbatim) with LDS-packed coalesced Bu stores ----
__global__ __launch_bounds__(256) void gemm1(const bf16* __restrict__ u,
                                             const bf16* __restrict__ Wp,
                                             bf16* __restrict__ Bu) {
    __shared__ bf16 As[128 * 32];
    __shared__ bf16 Bs[128 * 32];
    __shared__ bf16 Cs[128 * 136];       // +8 pad: spreads 2B-scatter banks
    const int tid = threadIdx.x;
    const int m0 = blockIdx.x * 128, n0 = blockIdx.y * 128;
    const int lane = tid & 63, w = tid >> 6;
    const int wm = (w >> 1) * 64, wn = (w & 1) * 64;
    const int lr16 = lane & 15, kq = (lane >> 4) * 8;
    const int srow = tid >> 2, scol = (tid & 3) * 8;

    f32x4 acc[4][4] = {};
    for (int k0 = 0; k0 < DIN; k0 += 32) {
        gl_lds16(u  + (size_t)(m0 + srow) * DIN + k0 + scol,       &As[tid * 8]);
        gl_lds16(u  + (size_t)(m0 + 64 + srow) * DIN + k0 + scol,  &As[2048 + tid * 8]);
        gl_lds16(Wp + (size_t)(n0 + srow) * DIN + k0 + scol,       &Bs[tid * 8]);
        gl_lds16(Wp + (size_t)(n0 + 64 + srow) * DIN + k0 + scol,  &Bs[2048 + tid * 8]);
        __syncthreads();
        bf16x8 af[4], bfr[4];
#pragma unroll
        for (int i = 0; i < 4; ++i)
            af[i] = *(const bf16x8*)(&As[(wm + i * 16 + lr16) * 32 + kq]);
#pragma unroll
        for (int j = 0; j < 4; ++j)
            bfr[j] = *(const bf16x8*)(&Bs[(wn + j * 16 + lr16) * 32 + kq]);
#pragma unroll
        for (int i = 0; i < 4; ++i)
#pragma unroll
            for (int j = 0; j < 4; ++j)
                acc[i][j] = __builtin_amdgcn_mfma_f32_16x16x32_bf16(af[i], bfr[j], acc[i][j], 0, 0, 0);
        __syncthreads();
    }
    const int crow = (lane >> 4) * 4, ccol = lane & 15;
#pragma unroll
    for (int i = 0; i < 4; ++i)
#pragma unroll
        for (int j = 0; j < 4; ++j)
#pragma unroll
            for (int r = 0; r < 4; ++r)
                Cs[(wm + i * 16 + crow + r) * 136 + wn + j * 16 + ccol] =
                    __float2bfloat16(acc[i][j][r]);
    __syncthreads();
#pragma unroll
    for (int p = 0; p < 8; ++p) {
        int row = p * 16 + (tid >> 4);
        int colg = (tid & 15) * 8;
        *(uint4*)(&Bu[(size_t)(m0 + row) * N1 + n0 + colg]) =
            *(const uint4*)(&Cs[row * 136 + colg]);
    }
}

// ---- scan phase 1 (baseline verbatim): per-(b,n,chunk) final state ----
__global__ __launch_bounds__(512) void scan1(const bf16* __restrict__ Bu,
                                             const float* __restrict__ lam,
                                             float* __restrict__ Ssum) {
    int n = threadIdx.x;
    int c = blockIdx.x;
    int b = blockIdx.y;
    float lr = lam[n], li = lam[NST + n];
    const bf16* base = Bu + ((size_t)b * T_LEN + (size_t)c * CHL) * N1;
    float sr = 0.f, si = 0.f;
    for (int j = 0; j < CHL; ++j) {
        float br = __bfloat162float(base[(size_t)j * N1 + n]);
        float bi = __bfloat162float(base[(size_t)j * N1 + NST + n]);
        float tr = lr * sr - li * si + br;
        float ti = lr * si + li * sr + bi;
        sr = tr; si = ti;
    }
    size_t o = ((size_t)b * NCH + c) * N1 + n;
    Ssum[o] = sr; Ssum[o + NST] = si;
}

// ---- scan phase 3 (baseline verbatim): inline carry over Ssum ----
__global__ __launch_bounds__(512) void scan3(bf16* __restrict__ Bu,
                                             const float* __restrict__ lam,
                                             const float* __restrict__ lamL,
                                             const float* __restrict__ Ssum) {
    int n = threadIdx.x, c = blockIdx.x, b = blockIdx.y;
    float lr = lam[n], li = lam[NST + n];
    float Lr = lamL[n], Li = lamL[NST + n];
    float pr = 0.f, pi = 0.f;
    for (int cp = 0; cp < c; ++cp) {
        size_t o = ((size_t)b * NCH + cp) * N1 + n;
        float sr = Ssum[o], si = Ssum[o + NST];
        float tr = Lr * pr - Li * pi + sr;
        float ti = Lr * pi + Li * pr + si;
        pr = tr; pi = ti;
    }
    float xr = pr, xi = pi;
    bf16* base = Bu + ((size_t)b * T_LEN + (size_t)c * CHL) * N1;
    for (int j = 0; j < CHL; ++j) {
        float br = __bfloat162float(base[(size_t)j * N1 + n]);
        float bi = __bfloat162float(base[(size_t)j * N1 + NST + n]);
        float tr = lr * xr - li * xi + br;
        float ti = lr * xi + li * xr + bi;
        xr = tr; xi = ti;
        base[(size_t)j * N1 + n]       = __float2bfloat16(xr);
        base[(size_t)j * N1 + NST + n] = __float2bfloat16(xi);
    }
}

// ---- GEMM2 v2: full DOUT per block, A read once ----
// Tile 64(M) x 256(N), 512 threads, 2x4 wave grid of 32x64, acc[2][4].
// Grid = 512 blocks (same parallelism as old (256,2)); A-panel streamed
// exactly once (saves ~80 MB HBM). Same K-order/MFMA shape -> y bitwise
// identical to baseline gemm2.
__global__ __launch_bounds__(512) void gemm2(const bf16* __restrict__ X,
                                             const bf16* __restrict__ u,
                                             const bf16* __restrict__ W2,
                                             float* __restrict__ y) {
    __shared__ bf16 As[64 * 32];
    __shared__ bf16 Bs[256 * 32];
    const int tid = threadIdx.x;
    const int m0 = blockIdx.x * 64;
    const int lane = tid & 63, w = tid >> 6;
    const int wm = (w >> 2) * 32, wn = (w & 3) * 64;   // 2x4 wave grid, 32x64 each
    const int lr16 = lane & 15, kq = (lane >> 4) * 8;
    const int arow = tid >> 2, acol = (tid & 3) * 8;   // threads 0..255 stage A rows 0..63
    const int brow = tid >> 2, bcol = (tid & 3) * 8;   // all 512 stage B rows 0..127 (+128)

    f32x4 acc[2][4] = {};
    for (int k0 = 0; k0 < K2; k0 += 32) {
        const bf16* Asrc; size_t lda; int kc;
        if (k0 < N1) { Asrc = X; lda = N1;  kc = k0; }
        else         { Asrc = u; lda = DIN; kc = k0 - N1; }
        if (tid < 256)
            gl_lds16(Asrc + (size_t)(m0 + arow) * lda + kc + acol, &As[tid * 8]);
        gl_lds16(W2 + (size_t)brow * K2 + k0 + bcol,         &Bs[tid * 8]);
        gl_lds16(W2 + (size_t)(128 + brow) * K2 + k0 + bcol, &Bs[4096 + tid * 8]);
        __syncthreads();
        bf16x8 af[2], bfr[4];
#pragma unroll
        for (int i = 0; i < 2; ++i)
            af[i] = *(const bf16x8*)(&As[(wm + i * 16 + lr16) * 32 + kq]);
#pragma unroll
        for (int j = 0; j < 4; ++j)
            bfr[j] = *(const bf16x8*)(&Bs[(wn + j * 16 + lr16) * 32 + kq]);
#pragma unroll
        for (int i = 0; i < 2; ++i)
#pragma unroll
            for (int j = 0; j < 4; ++j)
                acc[i][j] = __builtin_amdgcn_mfma_f32_16x16x32_bf16(af[i], bfr[j], acc[i][j], 0, 0, 0);
        __syncthreads();
    }
    const int crow = (lane >> 4) * 4, ccol = lane & 15;
#pragma unroll
    for (int i = 0; i < 2; ++i)
#pragma unroll
        for (int j = 0; j < 4; ++j)
#pragma unroll
            for (int r = 0; r < 4; ++r)
                y[(size_t)(m0 + wm + i * 16 + crow + r) * DOUT + wn + j * 16 + ccol] =
                    acc[i][j][r];
}

extern "C" void kernel_launch(void* const* d_in, const int* in_sizes, int n_in,
                              void* d_out, int out_size, void* d_ws, size_t ws_size,
                              hipStream_t stream) {
    const float* u_in      = (const float*)d_in[0];
    const float* nu_log    = (const float*)d_in[1];
    const float* theta_log = (const float*)d_in[2];
    const float* gamma_log = (const float*)d_in[3];
    const float* B_real    = (const float*)d_in[4];
    const float* B_imag    = (const float*)d_in[5];
    const float* C_real    = (const float*)d_in[6];
    const float* C_imag    = (const float*)d_in[7];
    const float* Dm        = (const float*)d_in[8];
    float* y = (float*)d_out;
    char* ws = (char*)d_ws;

    bf16*  Bu   = (bf16*)ws;
    bf16*  u_bf = (bf16*)(ws + OFF_UBF);
    bf16*  Wp   = (bf16*)(ws + OFF_WP);
    bf16*  W2   = (bf16*)(ws + OFF_W2);
    float* lam  = (float*)(ws + OFF_LAM);
    float* lamL = (float*)(ws + OFF_LAML);
    float* Ssum = (float*)(ws + OFF_SSUM);

    prep<<<10496, 256, 0, stream>>>(u_in, nu_log, theta_log, gamma_log,
                                    B_real, B_imag, C_real, C_imag, Dm,
                                    u_bf, Wp, W2, lam, lamL);
    gemm1<<<dim3(M_ROWS / 128, N1 / 128), 256, 0, stream>>>(u_bf, Wp, Bu);
    scan1<<<dim3(NCH, B_SZ), 512, 0, stream>>>(Bu, lam, Ssum);
    scan3<<<dim3(NCH, B_SZ), 512, 0, stream>>>(Bu, lam, lamL, Ssum);
    gemm2<<<dim3(M_ROWS / 64), 512, 0, stream>>>(Bu, u_bf, W2, y);
}

// Round 4
// 192.963 us; speedup vs baseline: 1.1018x; 1.0497x over previous
//
#include <hip/hip_runtime.h>
#include <hip/hip_bf16.h>
#include <math.h>

#define B_SZ    8
#define T_LEN   4096
#define DIN     256
#define DOUT    256
#define NST     512
#define M_ROWS  (B_SZ * T_LEN)   // 32768
#define N1      (2 * NST)        // 1024: cols [0,512)=real plane, [512,1024)=imag plane
#define K2      (N1 + DIN)       // 1280
#define CHL     128              // scan chunk length
#define NCH     (T_LEN / CHL)    // 32

typedef __attribute__((ext_vector_type(8))) short bf16x8;
typedef __attribute__((ext_vector_type(4))) float f32x4;
typedef __hip_bfloat16 bf16;

// ws byte offsets (baseline layout)
#define OFF_UBF  67108864
#define OFF_WP   83886080
#define OFF_W2   84410368
#define OFF_LAM  85065728
#define OFF_LAML 85069824
#define OFF_SSUM 85073920

__device__ __forceinline__ void gl_lds16(const bf16* g, bf16* l) {
    __builtin_amdgcn_global_load_lds(
        (const __attribute__((address_space(1))) void*)g,
        (__attribute__((address_space(3))) void*)l, 16, 0, 0);
}

// ---- prep (baseline verbatim) ----
__global__ __launch_bounds__(256) void prep(const float* __restrict__ u,
        const float* __restrict__ nu_log, const float* __restrict__ theta_log,
        const float* __restrict__ gamma_log,
        const float* __restrict__ B_real, const float* __restrict__ B_imag,
        const float* __restrict__ C_real, const float* __restrict__ C_imag,
        const float* __restrict__ Dm,
        bf16* __restrict__ ub, bf16* __restrict__ Wp, bf16* __restrict__ W2,
        float* __restrict__ lam, float* __restrict__ lamL) {
    int bid = blockIdx.x, tid = threadIdx.x;
    if (bid < 8192) {                       // u -> bf16
        int i = bid * 256 + tid;
        float4 v = ((const float4*)u)[i];
        union { bf16 h[4]; uint2 u2; } p;
        p.h[0] = __float2bfloat16(v.x); p.h[1] = __float2bfloat16(v.y);
        p.h[2] = __float2bfloat16(v.z); p.h[3] = __float2bfloat16(v.w);
        ((uint2*)ub)[i] = p.u2;
    } else if (bid < 9216) {                // Wp (split planes) + lam/lamL
        int c = bid - 8192;                 // 0..1023
        int n = c & (NST - 1);
        float g = expf(gamma_log[n]);
        const float* src = (c < NST) ? (B_real + (size_t)n * DIN)
                                     : (B_imag + (size_t)n * DIN);
        Wp[(size_t)c * DIN + tid] = __float2bfloat16(g * src[tid]);
        int idx = c * 256 + tid;
        if (idx < NST) {
            float lm = expf(-expf(nu_log[idx]));
            float th = expf(theta_log[idx]);
            float lr = lm * cosf(th), li = lm * sinf(th);
            lam[idx] = lr; lam[NST + idx] = li;
            float ar = lr, ai = li;
#pragma unroll
            for (int q = 0; q < 7; ++q) {   // lambda^128
                float nr = ar * ar - ai * ai;
                float ni = 2.f * ar * ai;
                ar = nr; ai = ni;
            }
            lamL[idx] = ar; lamL[NST + idx] = ai;
        }
    } else {                                // W2 = [2Cr | -2Ci | D] split
        int idx = (bid - 9216) * 256 + tid;
        if (idx < DOUT * K2) {
            int o = idx / K2, c = idx - o * K2;
            float v;
            if (c < NST)            v =  2.0f * C_real[(size_t)o * NST + c];
            else if (c < 2 * NST)   v = -2.0f * C_imag[(size_t)o * NST + (c - NST)];
            else                    v =  Dm[(size_t)o * DIN + (c - 2 * NST)];
            W2[idx] = __float2bfloat16(v);
        }
    }
}

// ---- GEMM1 v2: double-buffered prefetch (STAGE(t+1) before compute(t)),
// single __syncthreads per K-step; Cs epilogue tile aliases the A/B dbuf
// (union) -> LDS 34.8 KB (was 50.6) -> 4 blocks/CU. Numerics identical. ----
__global__ __launch_bounds__(256) void gemm1(const bf16* __restrict__ u,
                                             const bf16* __restrict__ Wp,
                                             bf16* __restrict__ Bu) {
    __shared__ union {
        bf16 ab[2][2][128 * 32];   // [buf][A=0/B=1][row*32+col]
        bf16 cs[128 * 136];        // epilogue C-tile (+8 pad)
    } sm;
    const int tid = threadIdx.x;
    const int m0 = blockIdx.x * 128, n0 = blockIdx.y * 128;
    const int lane = tid & 63, w = tid >> 6;
    const int wm = (w >> 1) * 64, wn = (w & 1) * 64;
    const int lr16 = lane & 15, kq = (lane >> 4) * 8;
    const int srow = tid >> 2, scol = (tid & 3) * 8;

    f32x4 acc[4][4] = {};
    // prologue: stage panel 0 into buf 0
    {
        gl_lds16(u  + (size_t)(m0 + srow) * DIN + scol,       &sm.ab[0][0][tid * 8]);
        gl_lds16(u  + (size_t)(m0 + 64 + srow) * DIN + scol,  &sm.ab[0][0][2048 + tid * 8]);
        gl_lds16(Wp + (size_t)(n0 + srow) * DIN + scol,       &sm.ab[0][1][tid * 8]);
        gl_lds16(Wp + (size_t)(n0 + 64 + srow) * DIN + scol,  &sm.ab[0][1][2048 + tid * 8]);
    }
    __syncthreads();
    for (int t = 0; t < 8; ++t) {
        const int cur = t & 1;
        if (t < 7) {                       // prefetch next panel into other buf
            int k0 = (t + 1) * 32;
            gl_lds16(u  + (size_t)(m0 + srow) * DIN + k0 + scol,       &sm.ab[cur ^ 1][0][tid * 8]);
            gl_lds16(u  + (size_t)(m0 + 64 + srow) * DIN + k0 + scol,  &sm.ab[cur ^ 1][0][2048 + tid * 8]);
            gl_lds16(Wp + (size_t)(n0 + srow) * DIN + k0 + scol,       &sm.ab[cur ^ 1][1][tid * 8]);
            gl_lds16(Wp + (size_t)(n0 + 64 + srow) * DIN + k0 + scol,  &sm.ab[cur ^ 1][1][2048 + tid * 8]);
        }
        bf16x8 af[4], bfr[4];
#pragma unroll
        for (int i = 0; i < 4; ++i)
            af[i] = *(const bf16x8*)(&sm.ab[cur][0][(wm + i * 16 + lr16) * 32 + kq]);
#pragma unroll
        for (int j = 0; j < 4; ++j)
            bfr[j] = *(const bf16x8*)(&sm.ab[cur][1][(wn + j * 16 + lr16) * 32 + kq]);
#pragma unroll
        for (int i = 0; i < 4; ++i)
#pragma unroll
            for (int j = 0; j < 4; ++j)
                acc[i][j] = __builtin_amdgcn_mfma_f32_16x16x32_bf16(af[i], bfr[j], acc[i][j], 0, 0, 0);
        __syncthreads();                   // drains prefetch (latency hidden by compute)
    }
    const int crow = (lane >> 4) * 4, ccol = lane & 15;
#pragma unroll
    for (int i = 0; i < 4; ++i)
#pragma unroll
        for (int j = 0; j < 4; ++j)
#pragma unroll
            for (int r = 0; r < 4; ++r)
                sm.cs[(wm + i * 16 + crow + r) * 136 + wn + j * 16 + ccol] =
                    __float2bfloat16(acc[i][j][r]);
    __syncthreads();
#pragma unroll
    for (int p = 0; p < 8; ++p) {
        int row = p * 16 + (tid >> 4);
        int colg = (tid & 15) * 8;
        *(uint4*)(&Bu[(size_t)(m0 + row) * N1 + n0 + colg]) =
            *(const uint4*)(&sm.cs[row * 136 + colg]);
    }
}

// ---- scan phase 1 (baseline verbatim) ----
__global__ __launch_bounds__(512) void scan1(const bf16* __restrict__ Bu,
                                             const float* __restrict__ lam,
                                             float* __restrict__ Ssum) {
    int n = threadIdx.x;
    int c = blockIdx.x;
    int b = blockIdx.y;
    float lr = lam[n], li = lam[NST + n];
    const bf16* base = Bu + ((size_t)b * T_LEN + (size_t)c * CHL) * N1;
    float sr = 0.f, si = 0.f;
    for (int j = 0; j < CHL; ++j) {
        float br = __bfloat162float(base[(size_t)j * N1 + n]);
        float bi = __bfloat162float(base[(size_t)j * N1 + NST + n]);
        float tr = lr * sr - li * si + br;
        float ti = lr * si + li * sr + bi;
        sr = tr; si = ti;
    }
    size_t o = ((size_t)b * NCH + c) * N1 + n;
    Ssum[o] = sr; Ssum[o + NST] = si;
}

// ---- scan phase 3 (baseline verbatim): inline carry over Ssum ----
__global__ __launch_bounds__(512) void scan3(bf16* __restrict__ Bu,
                                             const float* __restrict__ lam,
                                             const float* __restrict__ lamL,
                                             const float* __restrict__ Ssum) {
    int n = threadIdx.x, c = blockIdx.x, b = blockIdx.y;
    float lr = lam[n], li = lam[NST + n];
    float Lr = lamL[n], Li = lamL[NST + n];
    float pr = 0.f, pi = 0.f;
    for (int cp = 0; cp < c; ++cp) {
        size_t o = ((size_t)b * NCH + cp) * N1 + n;
        float sr = Ssum[o], si = Ssum[o + NST];
        float tr = Lr * pr - Li * pi + sr;
        float ti = Lr * pi + Li * pr + si;
        pr = tr; pi = ti;
    }
    float xr = pr, xi = pi;
    bf16* base = Bu + ((size_t)b * T_LEN + (size_t)c * CHL) * N1;
    for (int j = 0; j < CHL; ++j) {
        float br = __bfloat162float(base[(size_t)j * N1 + n]);
        float bi = __bfloat162float(base[(size_t)j * N1 + NST + n]);
        float tr = lr * xr - li * xi + br;
        float ti = lr * xi + li * xr + bi;
        xr = tr; xi = ti;
        base[(size_t)j * N1 + n]       = __float2bfloat16(xr);
        base[(size_t)j * N1 + NST + n] = __float2bfloat16(xi);
    }
}

// ---- GEMM2 v3: baseline 128x128 shape + double-buffered prefetch,
// single __syncthreads per K-step. grid (256,2), 512 thr / 8 waves. ----
__global__ __launch_bounds__(512) void gemm2(const bf16* __restrict__ X,
                                             const bf16* __restrict__ u,
                                             const bf16* __restrict__ W2,
                                             float* __restrict__ y) {
    __shared__ bf16 ab[2][2][128 * 32];   // [buf][A=0/B=1] 32 KB total
    const int tid = threadIdx.x;
    const int m0 = blockIdx.x * 128, n0 = blockIdx.y * 128;
    const int lane = tid & 63, w = tid >> 6;
    const int wm = (w >> 2) * 64, wn = (w & 3) * 32;   // 2x4 wave grid, 64x32 each
    const int lr16 = lane & 15, kq = (lane >> 4) * 8;
    const int srow = tid >> 2, scol = (tid & 3) * 8;   // 512 threads cover 128 rows

    f32x4 acc[4][2] = {};
    // prologue: stage K-panel 0 (from X) into buf 0
    gl_lds16(X  + (size_t)(m0 + srow) * N1 + scol,  &ab[0][0][tid * 8]);
    gl_lds16(W2 + (size_t)(n0 + srow) * K2 + scol,  &ab[0][1][tid * 8]);
    __syncthreads();
    for (int t = 0; t < 40; ++t) {
        const int cur = t & 1;
        if (t < 39) {                      // prefetch panel t+1 into other buf
            int k0 = (t + 1) * 32;
            const bf16* Asrc; size_t lda; int kc;
            if (k0 < N1) { Asrc = X; lda = N1;  kc = k0; }
            else         { Asrc = u; lda = DIN; kc = k0 - N1; }
            gl_lds16(Asrc + (size_t)(m0 + srow) * lda + kc + scol, &ab[cur ^ 1][0][tid * 8]);
            gl_lds16(W2 + (size_t)(n0 + srow) * K2 + k0 + scol,    &ab[cur ^ 1][1][tid * 8]);
        }
        bf16x8 af[4], bfr[2];
#pragma unroll
        for (int i = 0; i < 4; ++i)
            af[i] = *(const bf16x8*)(&ab[cur][0][(wm + i * 16 + lr16) * 32 + kq]);
#pragma unroll
        for (int j = 0; j < 2; ++j)
            bfr[j] = *(const bf16x8*)(&ab[cur][1][(wn + j * 16 + lr16) * 32 + kq]);
#pragma unroll
        for (int i = 0; i < 4; ++i)
#pragma unroll
            for (int j = 0; j < 2; ++j)
                acc[i][j] = __builtin_amdgcn_mfma_f32_16x16x32_bf16(af[i], bfr[j], acc[i][j], 0, 0, 0);
        __syncthreads();                   // drains prefetch (latency hidden by compute)
    }
    const int crow = (lane >> 4) * 4, ccol = lane & 15;
#pragma unroll
    for (int i = 0; i < 4; ++i)
#pragma unroll
        for (int j = 0; j < 2; ++j)
#pragma unroll
            for (int r = 0; r < 4; ++r)
                y[(size_t)(m0 + wm + i * 16 + crow + r) * DOUT + n0 + wn + j * 16 + ccol] = acc[i][j][r];
}

extern "C" void kernel_launch(void* const* d_in, const int* in_sizes, int n_in,
                              void* d_out, int out_size, void* d_ws, size_t ws_size,
                              hipStream_t stream) {
    const float* u_in      = (const float*)d_in[0];
    const float* nu_log    = (const float*)d_in[1];
    const float* theta_log = (const float*)d_in[2];
    const float* gamma_log = (const float*)d_in[3];
    const float* B_real    = (const float*)d_in[4];
    const float* B_imag    = (const float*)d_in[5];
    const float* C_real    = (const float*)d_in[6];
    const float* C_imag    = (const float*)d_in[7];
    const float* Dm        = (const float*)d_in[8];
    float* y = (float*)d_out;
    char* ws = (char*)d_ws;

    bf16*  Bu   = (bf16*)ws;
    bf16*  u_bf = (bf16*)(ws + OFF_UBF);
    bf16*  Wp   = (bf16*)(ws + OFF_WP);
    bf16*  W2   = (bf16*)(ws + OFF_W2);
    float* lam  = (float*)(ws + OFF_LAM);
    float* lamL = (float*)(ws + OFF_LAML);
    float* Ssum = (float*)(ws + OFF_SSUM);

    prep<<<10496, 256, 0, stream>>>(u_in, nu_log, theta_log, gamma_log,
                                    B_real, B_imag, C_real, C_imag, Dm,
                                    u_bf, Wp, W2, lam, lamL);
    gemm1<<<dim3(M_ROWS / 128, N1 / 128), 256, 0, stream>>>(u_bf, Wp, Bu);
    scan1<<<dim3(NCH, B_SZ), 512, 0, stream>>>(Bu, lam, Ssum);
    scan3<<<dim3(NCH, B_SZ), 512, 0, stream>>>(Bu, lam, lamL, Ssum);
    gemm2<<<dim3(M_ROWS / 128, DOUT / 128), 512, 0, stream>>>(Bu, u_bf, W2, y);
}

// Round 9
// 188.223 us; speedup vs baseline: 1.1295x; 1.0252x over previous
//
#include <hip/hip_runtime.h>
#include <hip/hip_bf16.h>
#include <math.h>

#define B_SZ    8
#define T_LEN   4096
#define DIN     256
#define DOUT    256
#define NST     512
#define M_ROWS  (B_SZ * T_LEN)   // 32768
#define N1      (2 * NST)        // 1024: cols [0,512)=real plane, [512,1024)=imag plane
#define K2      (N1 + DIN)       // 1280
#define CHL     128              // scan chunk length
#define NCH     (T_LEN / CHL)    // 32

typedef __attribute__((ext_vector_type(8))) short bf16x8;
typedef __attribute__((ext_vector_type(4))) float f32x4;
typedef __hip_bfloat16 bf16;

// ws byte offsets (baseline layout)
#define OFF_UBF  67108864
#define OFF_WP   83886080
#define OFF_W2   84410368
#define OFF_LAM  85065728
#define OFF_LAML 85069824
#define OFF_SSUM 85073920

__device__ __forceinline__ void gl_lds16(const bf16* g, bf16* l) {
    __builtin_amdgcn_global_load_lds(
        (const __attribute__((address_space(1))) void*)g,
        (__attribute__((address_space(3))) void*)l, 16, 0, 0);
}

// ---- prep (baseline verbatim) ----
__global__ __launch_bounds__(256) void prep(const float* __restrict__ u,
        const float* __restrict__ nu_log, const float* __restrict__ theta_log,
        const float* __restrict__ gamma_log,
        const float* __restrict__ B_real, const float* __restrict__ B_imag,
        const float* __restrict__ C_real, const float* __restrict__ C_imag,
        const float* __restrict__ Dm,
        bf16* __restrict__ ub, bf16* __restrict__ Wp, bf16* __restrict__ W2,
        float* __restrict__ lam, float* __restrict__ lamL) {
    int bid = blockIdx.x, tid = threadIdx.x;
    if (bid < 8192) {                       // u -> bf16
        int i = bid * 256 + tid;
        float4 v = ((const float4*)u)[i];
        union { bf16 h[4]; uint2 u2; } p;
        p.h[0] = __float2bfloat16(v.x); p.h[1] = __float2bfloat16(v.y);
        p.h[2] = __float2bfloat16(v.z); p.h[3] = __float2bfloat16(v.w);
        ((uint2*)ub)[i] = p.u2;
    } else if (bid < 9216) {                // Wp (split planes) + lam/lamL
        int c = bid - 8192;                 // 0..1023
        int n = c & (NST - 1);
        float g = expf(gamma_log[n]);
        const float* src = (c < NST) ? (B_real + (size_t)n * DIN)
                                     : (B_imag + (size_t)n * DIN);
        Wp[(size_t)c * DIN + tid] = __float2bfloat16(g * src[tid]);
        int idx = c * 256 + tid;
        if (idx < NST) {
            float lm = expf(-expf(nu_log[idx]));
            float th = expf(theta_log[idx]);
            float lr = lm * cosf(th), li = lm * sinf(th);
            lam[idx] = lr; lam[NST + idx] = li;
            float ar = lr, ai = li;
#pragma unroll
            for (int q = 0; q < 7; ++q) {   // lambda^128
                float nr = ar * ar - ai * ai;
                float ni = 2.f * ar * ai;
                ar = nr; ai = ni;
            }
            lamL[idx] = ar; lamL[NST + idx] = ai;
        }
    } else {                                // W2 = [2Cr | -2Ci | D] split
        int idx = (bid - 9216) * 256 + tid;
        if (idx < DOUT * K2) {
            int o = idx / K2, c = idx - o * K2;
            float v;
            if (c < NST)            v =  2.0f * C_real[(size_t)o * NST + c];
            else if (c < 2 * NST)   v = -2.0f * C_imag[(size_t)o * NST + (c - NST)];
            else                    v =  Dm[(size_t)o * DIN + (c - 2 * NST)];
            W2[idx] = __float2bfloat16(v);
        }
    }
}

// ---- GEMM1 (R4-verified): dbuf prefetch, single __syncthreads per K-step;
// Cs epilogue tile aliases the A/B dbuf (union) ----
__global__ __launch_bounds__(256) void gemm1(const bf16* __restrict__ u,
                                             const bf16* __restrict__ Wp,
                                             bf16* __restrict__ Bu) {
    __shared__ union {
        bf16 ab[2][2][128 * 32];   // [buf][A=0/B=1][row*32+col]
        bf16 cs[128 * 136];        // epilogue C-tile (+8 pad)
    } sm;
    const int tid = threadIdx.x;
    const int m0 = blockIdx.x * 128, n0 = blockIdx.y * 128;
    const int lane = tid & 63, w = tid >> 6;
    const int wm = (w >> 1) * 64, wn = (w & 1) * 64;
    const int lr16 = lane & 15, kq = (lane >> 4) * 8;
    const int srow = tid >> 2, scol = (tid & 3) * 8;

    f32x4 acc[4][4] = {};
    // prologue: stage panel 0 into buf 0
    {
        gl_lds16(u  + (size_t)(m0 + srow) * DIN + scol,       &sm.ab[0][0][tid * 8]);
        gl_lds16(u  + (size_t)(m0 + 64 + srow) * DIN + scol,  &sm.ab[0][0][2048 + tid * 8]);
        gl_lds16(Wp + (size_t)(n0 + srow) * DIN + scol,       &sm.ab[0][1][tid * 8]);
        gl_lds16(Wp + (size_t)(n0 + 64 + srow) * DIN + scol,  &sm.ab[0][1][2048 + tid * 8]);
    }
    __syncthreads();
    for (int t = 0; t < 8; ++t) {
        const int cur = t & 1;
        if (t < 7) {                       // prefetch next panel into other buf
            int k0 = (t + 1) * 32;
            gl_lds16(u  + (size_t)(m0 + srow) * DIN + k0 + scol,       &sm.ab[cur ^ 1][0][tid * 8]);
            gl_lds16(u  + (size_t)(m0 + 64 + srow) * DIN + k0 + scol,  &sm.ab[cur ^ 1][0][2048 + tid * 8]);
            gl_lds16(Wp + (size_t)(n0 + srow) * DIN + k0 + scol,       &sm.ab[cur ^ 1][1][tid * 8]);
            gl_lds16(Wp + (size_t)(n0 + 64 + srow) * DIN + k0 + scol,  &sm.ab[cur ^ 1][1][2048 + tid * 8]);
        }
        bf16x8 af[4], bfr[4];
#pragma unroll
        for (int i = 0; i < 4; ++i)
            af[i] = *(const bf16x8*)(&sm.ab[cur][0][(wm + i * 16 + lr16) * 32 + kq]);
#pragma unroll
        for (int j = 0; j < 4; ++j)
            bfr[j] = *(const bf16x8*)(&sm.ab[cur][1][(wn + j * 16 + lr16) * 32 + kq]);
#pragma unroll
        for (int i = 0; i < 4; ++i)
#pragma unroll
            for (int j = 0; j < 4; ++j)
                acc[i][j] = __builtin_amdgcn_mfma_f32_16x16x32_bf16(af[i], bfr[j], acc[i][j], 0, 0, 0);
        __syncthreads();                   // drains prefetch (latency hidden by compute)
    }
    const int crow = (lane >> 4) * 4, ccol = lane & 15;
#pragma unroll
    for (int i = 0; i < 4; ++i)
#pragma unroll
        for (int j = 0; j < 4; ++j)
#pragma unroll
            for (int r = 0; r < 4; ++r)
                sm.cs[(wm + i * 16 + crow + r) * 136 + wn + j * 16 + ccol] =
                    __float2bfloat16(acc[i][j][r]);
    __syncthreads();
#pragma unroll
    for (int p = 0; p < 8; ++p) {
        int row = p * 16 + (tid >> 4);
        int colg = (tid & 15) * 8;
        *(uint4*)(&Bu[(size_t)(m0 + row) * N1 + n0 + colg]) =
            *(const uint4*)(&sm.cs[row * 136 + colg]);
    }
}

// ---- scan phase 1: baseline + unroll-8 load batching.
// The 16 loads of 8 iterations are address-independent of the recurrence;
// unrolling lets the compiler issue them ahead of the serial FMA chain
// (1 block/CU -> latency-bound without this). Arithmetic order unchanged.
__global__ __launch_bounds__(512) void scan1(const bf16* __restrict__ Bu,
                                             const float* __restrict__ lam,
                                             float* __restrict__ Ssum) {
    int n = threadIdx.x;
    int c = blockIdx.x;
    int b = blockIdx.y;
    float lr = lam[n], li = lam[NST + n];
    const bf16* base = Bu + ((size_t)b * T_LEN + (size_t)c * CHL) * N1;
    float sr = 0.f, si = 0.f;
#pragma unroll 8
    for (int j = 0; j < CHL; ++j) {
        float br = __bfloat162float(base[(size_t)j * N1 + n]);
        float bi = __bfloat162float(base[(size_t)j * N1 + NST + n]);
        float tr = lr * sr - li * si + br;
        float ti = lr * si + li * sr + bi;
        sr = tr; si = ti;
    }
    size_t o = ((size_t)b * NCH + c) * N1 + n;
    Ssum[o] = sr; Ssum[o + NST] = si;
}

// ---- scan phase 3: baseline + unroll load batching (carry: L2 reads) ----
__global__ __launch_bounds__(512) void scan3(bf16* __restrict__ Bu,
                                             const float* __restrict__ lam,
                                             const float* __restrict__ lamL,
                                             const float* __restrict__ Ssum) {
    int n = threadIdx.x, c = blockIdx.x, b = blockIdx.y;
    float lr = lam[n], li = lam[NST + n];
    float Lr = lamL[n], Li = lamL[NST + n];
    float pr = 0.f, pi = 0.f;
#pragma unroll 4
    for (int cp = 0; cp < c; ++cp) {
        size_t o = ((size_t)b * NCH + cp) * N1 + n;
        float sr = Ssum[o], si = Ssum[o + NST];
        float tr = Lr * pr - Li * pi + sr;
        float ti = Lr * pi + Li * pr + si;
        pr = tr; pi = ti;
    }
    float xr = pr, xi = pi;
    bf16* base = Bu + ((size_t)b * T_LEN + (size_t)c * CHL) * N1;
#pragma unroll 8
    for (int j = 0; j < CHL; ++j) {
        float br = __bfloat162float(base[(size_t)j * N1 + n]);
        float bi = __bfloat162float(base[(size_t)j * N1 + NST + n]);
        float tr = lr * xr - li * xi + br;
        float ti = lr * xi + li * xr + bi;
        xr = tr; xi = ti;
        base[(size_t)j * N1 + n]       = __float2bfloat16(xr);
        base[(size_t)j * N1 + NST + n] = __float2bfloat16(xi);
    }
}

// ---- GEMM2 (R4-verified): 128x128 tile, dbuf prefetch ----
__global__ __launch_bounds__(512) void gemm2(const bf16* __restrict__ X,
                                             const bf16* __restrict__ u,
                                             const bf16* __restrict__ W2,
                                             float* __restrict__ y) {
    __shared__ bf16 ab[2][2][128 * 32];   // [buf][A=0/B=1] 32 KB total
    const int tid = threadIdx.x;
    const int m0 = blockIdx.x * 128, n0 = blockIdx.y * 128;
    const int lane = tid & 63, w = tid >> 6;
    const int wm = (w >> 2) * 64, wn = (w & 3) * 32;   // 2x4 wave grid, 64x32 each
    const int lr16 = lane & 15, kq = (lane >> 4) * 8;
    const int srow = tid >> 2, scol = (tid & 3) * 8;   // 512 threads cover 128 rows

    f32x4 acc[4][2] = {};
    gl_lds16(X  + (size_t)(m0 + srow) * N1 + scol,  &ab[0][0][tid * 8]);
    gl_lds16(W2 + (size_t)(n0 + srow) * K2 + scol,  &ab[0][1][tid * 8]);
    __syncthreads();
    for (int t = 0; t < 40; ++t) {
        const int cur = t & 1;
        if (t < 39) {                      // prefetch panel t+1 into other buf
            int k0 = (t + 1) * 32;
            const bf16* Asrc; size_t lda; int kc;
            if (k0 < N1) { Asrc = X; lda = N1;  kc = k0; }
            else         { Asrc = u; lda = DIN; kc = k0 - N1; }
            gl_lds16(Asrc + (size_t)(m0 + srow) * lda + kc + scol, &ab[cur ^ 1][0][tid * 8]);
            gl_lds16(W2 + (size_t)(n0 + srow) * K2 + k0 + scol,    &ab[cur ^ 1][1][tid * 8]);
        }
        bf16x8 af[4], bfr[2];
#pragma unroll
        for (int i = 0; i < 4; ++i)
            af[i] = *(const bf16x8*)(&ab[cur][0][(wm + i * 16 + lr16) * 32 + kq]);
#pragma unroll
        for (int j = 0; j < 2; ++j)
            bfr[j] = *(const bf16x8*)(&ab[cur][1][(wn + j * 16 + lr16) * 32 + kq]);
#pragma unroll
        for (int i = 0; i < 4; ++i)
#pragma unroll
            for (int j = 0; j < 2; ++j)
                acc[i][j] = __builtin_amdgcn_mfma_f32_16x16x32_bf16(af[i], bfr[j], acc[i][j], 0, 0, 0);
        __syncthreads();                   // drains prefetch (latency hidden by compute)
    }
    const int crow = (lane >> 4) * 4, ccol = lane & 15;
#pragma unroll
    for (int i = 0; i < 4; ++i)
#pragma unroll
        for (int j = 0; j < 2; ++j)
#pragma unroll
            for (int r = 0; r < 4; ++r)
                y[(size_t)(m0 + wm + i * 16 + crow + r) * DOUT + n0 + wn + j * 16 + ccol] = acc[i][j][r];
}

extern "C" void kernel_launch(void* const* d_in, const int* in_sizes, int n_in,
                              void* d_out, int out_size, void* d_ws, size_t ws_size,
                              hipStream_t stream) {
    const float* u_in      = (const float*)d_in[0];
    const float* nu_log    = (const float*)d_in[1];
    const float* theta_log = (const float*)d_in[2];
    const float* gamma_log = (const float*)d_in[3];
    const float* B_real    = (const float*)d_in[4];
    const float* B_imag    = (const float*)d_in[5];
    const float* C_real    = (const float*)d_in[6];
    const float* C_imag    = (const float*)d_in[7];
    const float* Dm        = (const float*)d_in[8];
    float* y = (float*)d_out;
    char* ws = (char*)d_ws;

    bf16*  Bu   = (bf16*)ws;
    bf16*  u_bf = (bf16*)(ws + OFF_UBF);
    bf16*  Wp   = (bf16*)(ws + OFF_WP);
    bf16*  W2   = (bf16*)(ws + OFF_W2);
    float* lam  = (float*)(ws + OFF_LAM);
    float* lamL = (float*)(ws + OFF_LAML);
    float* Ssum = (float*)(ws + OFF_SSUM);

    prep<<<10496, 256, 0, stream>>>(u_in, nu_log, theta_log, gamma_log,
                                    B_real, B_imag, C_real, C_imag, Dm,
                                    u_bf, Wp, W2, lam, lamL);
    gemm1<<<dim3(M_ROWS / 128, N1 / 128), 256, 0, stream>>>(u_bf, Wp, Bu);
    scan1<<<dim3(NCH, B_SZ), 512, 0, stream>>>(Bu, lam, Ssum);
    scan3<<<dim3(NCH, B_SZ), 512, 0, stream>>>(Bu, lam, lamL, Ssum);
    gemm2<<<dim3(M_ROWS / 128, DOUT / 128), 512, 0, stream>>>(Bu, u_bf, W2, y);
}

// Round 10
// 184.769 us; speedup vs baseline: 1.1506x; 1.0187x over previous
//
#include <hip/hip_runtime.h>
#include <hip/hip_bf16.h>
#include <math.h>

#define B_SZ    8
#define T_LEN   4096
#define DIN     256
#define DOUT    256
#define NST     512
#define M_ROWS  (B_SZ * T_LEN)   // 32768
#define N1      (2 * NST)        // 1024: cols [0,512)=real plane, [512,1024)=imag plane
#define K2      (N1 + DIN)       // 1280
#define CHL     128              // scan chunk length
#define NCH     (T_LEN / CHL)    // 32

typedef __attribute__((ext_vector_type(8))) short bf16x8;
typedef __attribute__((ext_vector_type(4))) float f32x4;
typedef __hip_bfloat16 bf16;

// ws byte offsets (baseline layout)
#define OFF_UBF  67108864
#define OFF_WP   83886080
#define OFF_W2   84410368
#define OFF_LAM  85065728
#define OFF_LAML 85069824
#define OFF_SSUM 85073920

__device__ __forceinline__ void gl_lds16(const bf16* g, bf16* l) {
    __builtin_amdgcn_global_load_lds(
        (const __attribute__((address_space(1))) void*)g,
        (__attribute__((address_space(3))) void*)l, 16, 0, 0);
}

// ---- prep (baseline verbatim) ----
__global__ __launch_bounds__(256) void prep(const float* __restrict__ u,
        const float* __restrict__ nu_log, const float* __restrict__ theta_log,
        const float* __restrict__ gamma_log,
        const float* __restrict__ B_real, const float* __restrict__ B_imag,
        const float* __restrict__ C_real, const float* __restrict__ C_imag,
        const float* __restrict__ Dm,
        bf16* __restrict__ ub, bf16* __restrict__ Wp, bf16* __restrict__ W2,
        float* __restrict__ lam, float* __restrict__ lamL) {
    int bid = blockIdx.x, tid = threadIdx.x;
    if (bid < 8192) {                       // u -> bf16
        int i = bid * 256 + tid;
        float4 v = ((const float4*)u)[i];
        union { bf16 h[4]; uint2 u2; } p;
        p.h[0] = __float2bfloat16(v.x); p.h[1] = __float2bfloat16(v.y);
        p.h[2] = __float2bfloat16(v.z); p.h[3] = __float2bfloat16(v.w);
        ((uint2*)ub)[i] = p.u2;
    } else if (bid < 9216) {                // Wp (split planes) + lam/lamL
        int c = bid - 8192;                 // 0..1023
        int n = c & (NST - 1);
        float g = expf(gamma_log[n]);
        const float* src = (c < NST) ? (B_real + (size_t)n * DIN)
                                     : (B_imag + (size_t)n * DIN);
        Wp[(size_t)c * DIN + tid] = __float2bfloat16(g * src[tid]);
        int idx = c * 256 + tid;
        if (idx < NST) {
            float lm = expf(-expf(nu_log[idx]));
            float th = expf(theta_log[idx]);
            float lr = lm * cosf(th), li = lm * sinf(th);
            lam[idx] = lr; lam[NST + idx] = li;
            float ar = lr, ai = li;
#pragma unroll
            for (int q = 0; q < 7; ++q) {   // lambda^128
                float nr = ar * ar - ai * ai;
                float ni = 2.f * ar * ai;
                ar = nr; ai = ni;
            }
            lamL[idx] = ar; lamL[NST + idx] = ai;
        }
    } else {                                // W2 = [2Cr | -2Ci | D] split
        int idx = (bid - 9216) * 256 + tid;
        if (idx < DOUT * K2) {
            int o = idx / K2, c = idx - o * K2;
            float v;
            if (c < NST)            v =  2.0f * C_real[(size_t)o * NST + c];
            else if (c < 2 * NST)   v = -2.0f * C_imag[(size_t)o * NST + (c - NST)];
            else                    v =  Dm[(size_t)o * DIN + (c - 2 * NST)];
            W2[idx] = __float2bfloat16(v);
        }
    }
}

// ---- GEMM1 (R4/R9-verified): dbuf prefetch, single __syncthreads per K-step;
// Cs epilogue tile aliases the A/B dbuf (union) ----
__global__ __launch_bounds__(256) void gemm1(const bf16* __restrict__ u,
                                             const bf16* __restrict__ Wp,
                                             bf16* __restrict__ Bu) {
    __shared__ union {
        bf16 ab[2][2][128 * 32];   // [buf][A=0/B=1][row*32+col]
        bf16 cs[128 * 136];        // epilogue C-tile (+8 pad)
    } sm;
    const int tid = threadIdx.x;
    const int m0 = blockIdx.x * 128, n0 = blockIdx.y * 128;
    const int lane = tid & 63, w = tid >> 6;
    const int wm = (w >> 1) * 64, wn = (w & 1) * 64;
    const int lr16 = lane & 15, kq = (lane >> 4) * 8;
    const int srow = tid >> 2, scol = (tid & 3) * 8;

    f32x4 acc[4][4] = {};
    // prologue: stage panel 0 into buf 0
    {
        gl_lds16(u  + (size_t)(m0 + srow) * DIN + scol,       &sm.ab[0][0][tid * 8]);
        gl_lds16(u  + (size_t)(m0 + 64 + srow) * DIN + scol,  &sm.ab[0][0][2048 + tid * 8]);
        gl_lds16(Wp + (size_t)(n0 + srow) * DIN + scol,       &sm.ab[0][1][tid * 8]);
        gl_lds16(Wp + (size_t)(n0 + 64 + srow) * DIN + scol,  &sm.ab[0][1][2048 + tid * 8]);
    }
    __syncthreads();
    for (int t = 0; t < 8; ++t) {
        const int cur = t & 1;
        if (t < 7) {                       // prefetch next panel into other buf
            int k0 = (t + 1) * 32;
            gl_lds16(u  + (size_t)(m0 + srow) * DIN + k0 + scol,       &sm.ab[cur ^ 1][0][tid * 8]);
            gl_lds16(u  + (size_t)(m0 + 64 + srow) * DIN + k0 + scol,  &sm.ab[cur ^ 1][0][2048 + tid * 8]);
            gl_lds16(Wp + (size_t)(n0 + srow) * DIN + k0 + scol,       &sm.ab[cur ^ 1][1][tid * 8]);
            gl_lds16(Wp + (size_t)(n0 + 64 + srow) * DIN + k0 + scol,  &sm.ab[cur ^ 1][1][2048 + tid * 8]);
        }
        bf16x8 af[4], bfr[4];
#pragma unroll
        for (int i = 0; i < 4; ++i)
            af[i] = *(const bf16x8*)(&sm.ab[cur][0][(wm + i * 16 + lr16) * 32 + kq]);
#pragma unroll
        for (int j = 0; j < 4; ++j)
            bfr[j] = *(const bf16x8*)(&sm.ab[cur][1][(wn + j * 16 + lr16) * 32 + kq]);
#pragma unroll
        for (int i = 0; i < 4; ++i)
#pragma unroll
            for (int j = 0; j < 4; ++j)
                acc[i][j] = __builtin_amdgcn_mfma_f32_16x16x32_bf16(af[i], bfr[j], acc[i][j], 0, 0, 0);
        __syncthreads();                   // drains prefetch (latency hidden by compute)
    }
    const int crow = (lane >> 4) * 4, ccol = lane & 15;
#pragma unroll
    for (int i = 0; i < 4; ++i)
#pragma unroll
        for (int j = 0; j < 4; ++j)
#pragma unroll
            for (int r = 0; r < 4; ++r)
                sm.cs[(wm + i * 16 + crow + r) * 136 + wn + j * 16 + ccol] =
                    __float2bfloat16(acc[i][j][r]);
    __syncthreads();
#pragma unroll
    for (int p = 0; p < 8; ++p) {
        int row = p * 16 + (tid >> 4);
        int colg = (tid & 15) * 8;
        *(uint4*)(&Bu[(size_t)(m0 + row) * N1 + n0 + colg]) =
            *(const uint4*)(&sm.cs[row * 136 + colg]);
    }
}

// ---- scan phase 1 (R9-verified): unroll-8 load batching ----
__global__ __launch_bounds__(512) void scan1(const bf16* __restrict__ Bu,
                                             const float* __restrict__ lam,
                                             float* __restrict__ Ssum) {
    int n = threadIdx.x;
    int c = blockIdx.x;
    int b = blockIdx.y;
    float lr = lam[n], li = lam[NST + n];
    const bf16* base = Bu + ((size_t)b * T_LEN + (size_t)c * CHL) * N1;
    float sr = 0.f, si = 0.f;
#pragma unroll 8
    for (int j = 0; j < CHL; ++j) {
        float br = __bfloat162float(base[(size_t)j * N1 + n]);
        float bi = __bfloat162float(base[(size_t)j * N1 + NST + n]);
        float tr = lr * sr - li * si + br;
        float ti = lr * si + li * sr + bi;
        sr = tr; si = ti;
    }
    size_t o = ((size_t)b * NCH + c) * N1 + n;
    Ssum[o] = sr; Ssum[o + NST] = si;
}

// ---- scan phase 3 (R9-verified): inline carry + unroll batching ----
__global__ __launch_bounds__(512) void scan3(bf16* __restrict__ Bu,
                                             const float* __restrict__ lam,
                                             const float* __restrict__ lamL,
                                             const float* __restrict__ Ssum) {
    int n = threadIdx.x, c = blockIdx.x, b = blockIdx.y;
    float lr = lam[n], li = lam[NST + n];
    float Lr = lamL[n], Li = lamL[NST + n];
    float pr = 0.f, pi = 0.f;
#pragma unroll 4
    for (int cp = 0; cp < c; ++cp) {
        size_t o = ((size_t)b * NCH + cp) * N1 + n;
        float sr = Ssum[o], si = Ssum[o + NST];
        float tr = Lr * pr - Li * pi + sr;
        float ti = Lr * pi + Li * pr + si;
        pr = tr; pi = ti;
    }
    float xr = pr, xi = pi;
    bf16* base = Bu + ((size_t)b * T_LEN + (size_t)c * CHL) * N1;
#pragma unroll 8
    for (int j = 0; j < CHL; ++j) {
        float br = __bfloat162float(base[(size_t)j * N1 + n]);
        float bi = __bfloat162float(base[(size_t)j * N1 + NST + n]);
        float tr = lr * xr - li * xi + br;
        float ti = lr * xi + li * xr + bi;
        xr = tr; xi = ti;
        base[(size_t)j * N1 + n]       = __float2bfloat16(xr);
        base[(size_t)j * N1 + NST + n] = __float2bfloat16(xi);
    }
}

// ---- GEMM2 v7: BK=64 (20 K-steps, 2x compute per barrier), dbuf
// __syncthreads structure (R4-verified sync), T2 XOR swizzle on the
// [128][64] LDS tiles (rule #21: linear gl_lds dest + inverse-swizzled
// GLOBAL source chunk + swizzled read addr). Fragments carry identical
// global values -> y bitwise identical. LDS 64 KB; grid 512 = 2 blk/CU
// either way, so no occupancy loss. ----
__global__ __launch_bounds__(512) void gemm2(const bf16* __restrict__ X,
                                             const bf16* __restrict__ u,
                                             const bf16* __restrict__ W2,
                                             float* __restrict__ y) {
    __shared__ bf16 ab[2][2][128 * 64];   // 64 KB
    const int tid = threadIdx.x;
    const int m0 = blockIdx.x * 128, n0 = blockIdx.y * 128;
    const int lane = tid & 63, w = tid >> 6;
    const int wm = (w >> 2) * 64, wn = (w & 3) * 32;   // 2x4 wave grid, 64x32 each
    const int lr16 = lane & 15, kq = (lane >> 4) * 8;
    const int srow = tid >> 3;                 // 0..63: staged row within 64-row half
    const int scolx = ((tid & 7) ^ (srow & 7)) * 8;   // inverse-swizzled global col chunk

    // stage a 128x64 panel: dest linear (tid*8 / +4096), src chunk XOR (srow&7).
    // rows +64 keep the same (row&7) so the same XOR applies.
#define G2STAGE(buf, t_) do { int k0_ = (t_) * 64;                                    \
        const bf16* Asrc_; size_t lda_; int kc_;                                      \
        if (k0_ < N1) { Asrc_ = X; lda_ = N1;  kc_ = k0_; }                           \
        else          { Asrc_ = u; lda_ = DIN; kc_ = k0_ - N1; }                      \
        gl_lds16(Asrc_ + (size_t)(m0 + srow) * lda_ + kc_ + scolx,      &ab[buf][0][tid * 8]);        \
        gl_lds16(Asrc_ + (size_t)(m0 + 64 + srow) * lda_ + kc_ + scolx, &ab[buf][0][4096 + tid * 8]); \
        gl_lds16(W2 + (size_t)(n0 + srow) * K2 + k0_ + scolx,           &ab[buf][1][tid * 8]);        \
        gl_lds16(W2 + (size_t)(n0 + 64 + srow) * K2 + k0_ + scolx,      &ab[buf][1][4096 + tid * 8]); \
    } while (0)

    f32x4 acc[4][2] = {};
    G2STAGE(0, 0);                     // panel 0
    __syncthreads();
    for (int t = 0; t < 20; ++t) {
        const int cur = t & 1;
        if (t < 19) G2STAGE(cur ^ 1, t + 1);   // prefetch next panel
#pragma unroll
        for (int ks = 0; ks < 2; ++ks) {       // two 32-wide sub-panels, ascending k
            const int gck = ks * 4 + (lane >> 4);        // global 16B chunk 0..7
            bf16x8 af[4], bfr[2];
#pragma unroll
            for (int i = 0; i < 4; ++i) {
                int row = wm + i * 16 + lr16;
                af[i] = *(const bf16x8*)(&ab[cur][0][row * 64 + ((gck ^ (lane & 7)) * 8)]);
            }
#pragma unroll
            for (int j = 0; j < 2; ++j) {
                int row = wn + j * 16 + lr16;
                bfr[j] = *(const bf16x8*)(&ab[cur][1][row * 64 + ((gck ^ (lane & 7)) * 8)]);
            }
#pragma unroll
            for (int i = 0; i < 4; ++i)
#pragma unroll
                for (int j = 0; j < 2; ++j)
                    acc[i][j] = __builtin_amdgcn_mfma_f32_16x16x32_bf16(af[i], bfr[j], acc[i][j], 0, 0, 0);
        }
        __syncthreads();                   // drains prefetch (hidden by 16-MFMA phase)
    }
#undef G2STAGE
    const int crow = (lane >> 4) * 4, ccol = lane & 15;
#pragma unroll
    for (int i = 0; i < 4; ++i)
#pragma unroll
        for (int j = 0; j < 2; ++j)
#pragma unroll
            for (int r = 0; r < 4; ++r)
                y[(size_t)(m0 + wm + i * 16 + crow + r) * DOUT + n0 + wn + j * 16 + ccol] = acc[i][j][r];
}

extern "C" void kernel_launch(void* const* d_in, const int* in_sizes, int n_in,
                              void* d_out, int out_size, void* d_ws, size_t ws_size,
                              hipStream_t stream) {
    const float* u_in      = (const float*)d_in[0];
    const float* nu_log    = (const float*)d_in[1];
    const float* theta_log = (const float*)d_in[2];
    const float* gamma_log = (const float*)d_in[3];
    const float* B_real    = (const float*)d_in[4];
    const float* B_imag    = (const float*)d_in[5];
    const float* C_real    = (const float*)d_in[6];
    const float* C_imag    = (const float*)d_in[7];
    const float* Dm        = (const float*)d_in[8];
    float* y = (float*)d_out;
    char* ws = (char*)d_ws;

    bf16*  Bu   = (bf16*)ws;
    bf16*  u_bf = (bf16*)(ws + OFF_UBF);
    bf16*  Wp   = (bf16*)(ws + OFF_WP);
    bf16*  W2   = (bf16*)(ws + OFF_W2);
    float* lam  = (float*)(ws + OFF_LAM);
    float* lamL = (float*)(ws + OFF_LAML);
    float* Ssum = (float*)(ws + OFF_SSUM);

    prep<<<10496, 256, 0, stream>>>(u_in, nu_log, theta_log, gamma_log,
                                    B_real, B_imag, C_real, C_imag, Dm,
                                    u_bf, Wp, W2, lam, lamL);
    gemm1<<<dim3(M_ROWS / 128, N1 / 128), 256, 0, stream>>>(u_bf, Wp, Bu);
    scan1<<<dim3(NCH, B_SZ), 512, 0, stream>>>(Bu, lam, Ssum);
    scan3<<<dim3(NCH, B_SZ), 512, 0, stream>>>(Bu, lam, lamL, Ssum);
    gemm2<<<dim3(M_ROWS / 128, DOUT / 128), 512, 0, stream>>>(Bu, u_bf, W2, y);
}